// Round 1
// baseline (457.831 us; speedup 1.0000x reference)
//
#include <hip/hip_runtime.h>
#include <hip/hip_bf16.h>

// ws layout (floats): 0=ce_sum 1=yuku_sum 2=yuku_sumsq 3=gather_sum 4=cos_sum 5=valid_cnt 6=oyun_sum 7=oyun_sumsq
#define WS_CE 0
#define WS_YSUM 1
#define WS_YSQ 2
#define WS_GATHER 3
#define WS_COS 4
#define WS_CNT 5
#define WS_OSUM 6
#define WS_OSQ 7

__device__ __forceinline__ float wave_sum(float v) {
#pragma unroll
    for (int off = 32; off > 0; off >>= 1) v += __shfl_xor(v, off, 64);
    return v;
}

__global__ void init_ws_kernel(float* ws) {
    if (threadIdx.x < 8) ws[threadIdx.x] = 0.f;
}

// One block (256 threads) per row: online logsumexp, then loss = lse - x[target].
__global__ __launch_bounds__(256) void ce_kernel(const float* __restrict__ logits,
                                                 const int* __restrict__ targets,
                                                 int V, float* ws) {
    const int row = blockIdx.x;
    const float* rowp = logits + (size_t)row * V;
    const float4* rp = (const float4*)rowp;
    const int nvec = V >> 2;
    float m = -INFINITY;
    float s = 0.f;
    for (int i = threadIdx.x; i < nvec; i += 256) {
        float4 v = rp[i];
        {
            float nm = fmaxf(m, v.x);
            s = s * __expf(m - nm) + __expf(v.x - nm);
            m = nm;
        }
        {
            float nm = fmaxf(m, v.y);
            s = s * __expf(m - nm) + __expf(v.y - nm);
            m = nm;
        }
        {
            float nm = fmaxf(m, v.z);
            s = s * __expf(m - nm) + __expf(v.z - nm);
            m = nm;
        }
        {
            float nm = fmaxf(m, v.w);
            s = s * __expf(m - nm) + __expf(v.w - nm);
            m = nm;
        }
    }
    // wave-level (m, s) combine
#pragma unroll
    for (int off = 32; off > 0; off >>= 1) {
        float om = __shfl_xor(m, off, 64);
        float os = __shfl_xor(s, off, 64);
        float nm = fmaxf(m, om);
        s = s * __expf(m - nm) + os * __expf(om - nm);
        m = nm;
    }
    __shared__ float sm[4], ss[4];
    const int wid = threadIdx.x >> 6;
    const int lane = threadIdx.x & 63;
    if (lane == 0) { sm[wid] = m; ss[wid] = s; }
    __syncthreads();
    if (threadIdx.x == 0) {
        float M = sm[0], S = ss[0];
#pragma unroll
        for (int w = 1; w < 4; ++w) {
            float nm = fmaxf(M, sm[w]);
            S = S * __expf(M - nm) + ss[w] * __expf(sm[w] - nm);
            M = nm;
        }
        float xt = rowp[targets[row]];
        atomicAdd(ws + WS_CE, M + logf(S) - xt);
    }
}

// sum + sumsq of a float array (grid-stride, one atomic pair per block)
__global__ __launch_bounds__(256) void stats_kernel(const float* __restrict__ x, int n,
                                                    float* ws, int sum_idx, int sq_idx) {
    float s = 0.f, sq = 0.f;
    for (int i = blockIdx.x * 256 + threadIdx.x; i < n; i += gridDim.x * 256) {
        float v = x[i];
        s += v;
        sq += v * v;
    }
    s = wave_sum(s);
    sq = wave_sum(sq);
    __shared__ float as_[4], aq_[4];
    const int wid = threadIdx.x >> 6;
    const int lane = threadIdx.x & 63;
    if (lane == 0) { as_[wid] = s; aq_[wid] = sq; }
    __syncthreads();
    if (threadIdx.x == 0) {
        atomicAdd(ws + sum_idx, as_[0] + as_[1] + as_[2] + as_[3]);
        atomicAdd(ws + sq_idx, aq_[0] + aq_[1] + aq_[2] + aq_[3]);
    }
}

// sum of vals[idx[i]]
__global__ __launch_bounds__(256) void gather_kernel(const float* __restrict__ vals,
                                                     const int* __restrict__ idx, int n,
                                                     float* ws) {
    float s = 0.f;
    for (int i = blockIdx.x * 256 + threadIdx.x; i < n; i += gridDim.x * 256)
        s += vals[idx[i]];
    s = wave_sum(s);
    __shared__ float as_[4];
    const int wid = threadIdx.x >> 6;
    const int lane = threadIdx.x & 63;
    if (lane == 0) as_[wid] = s;
    __syncthreads();
    if (threadIdx.x == 0)
        atomicAdd(ws + WS_GATHER, as_[0] + as_[1] + as_[2] + as_[3]);
}

// one wave per unit (D=64 -> lane per dimension), grid-stride over units
__global__ __launch_bounds__(256) void suru_kernel(const float* __restrict__ strat,
                                                   const int* __restrict__ komsu,
                                                   int n, int K, float* ws) {
    const int lane = threadIdx.x & 63;
    const int wid = threadIdx.x >> 6;
    const int nwave = gridDim.x * 4;
    float cos_sum = 0.f, cnt = 0.f;
    for (int u = blockIdx.x * 4 + wid; u < n; u += nwave) {
        float own = strat[(size_t)u * 64 + lane];
        const int* kp = komsu + (size_t)u * K;
        float acc = 0.f;
        for (int k = 0; k < K; ++k)
            acc += strat[(size_t)kp[k] * 64 + lane];
        float ort = acc / (float)K;
        float dot = wave_sum(own * ort);
        float b2 = wave_sum(own * own);
        float k2 = wave_sum(ort * ort);
        float bn = sqrtf(b2), knrm = sqrtf(k2);
        if (bn > 1e-8f && knrm > 1e-8f) {
            cos_sum += dot / (bn * knrm);
            cnt += 1.f;
        }
    }
    __shared__ float cs[4], cc[4];
    if (lane == 0) { cs[wid] = cos_sum; cc[wid] = cnt; }
    __syncthreads();
    if (threadIdx.x == 0) {
        atomicAdd(ws + WS_COS, cs[0] + cs[1] + cs[2] + cs[3]);
        atomicAdd(ws + WS_CNT, cc[0] + cc[1] + cc[2] + cc[3]);
    }
}

__global__ void finalize_kernel(const float* __restrict__ ws, float* __restrict__ out,
                                int n_tok, int n_birim) {
    if (threadIdx.x != 0 || blockIdx.x != 0) return;
    const float n = (float)n_birim;
    float temel = ws[WS_CE] / (float)n_tok;

    float ysum = ws[WS_YSUM];
    float ymean = ysum / n;
    float yvar = (ws[WS_YSQ] - ysum * ysum / n) / (n - 1.f);
    float denge = yvar / (ymean + 1e-8f);

    float cpu = ws[WS_GATHER] / (float)n_tok;

    float cnt = ws[WS_CNT];
    float uyum = cnt > 0.f ? ws[WS_COS] / fmaxf(cnt, 1.f) : 0.f;
    float suru = (uyum + 1.f) * 0.5f;

    float osum = ws[WS_OSUM];
    float omean = osum / n;
    float ovar = (ws[WS_OSQ] - osum * osum / n) / (n - 1.f);
    float nash = ovar / (omean + 1e-8f);

    float toplam = 1.0f * temel + 0.1f * denge - 0.05f * cpu - 0.03f * suru + 0.02f * nash;
    out[0] = toplam;
    out[1] = temel;
    out[2] = denge;
    out[3] = cpu;
    out[4] = suru;
    out[5] = nash;
}

extern "C" void kernel_launch(void* const* d_in, const int* in_sizes, int n_in,
                              void* d_out, int out_size, void* d_ws, size_t ws_size,
                              hipStream_t stream) {
    const float* tahminler = (const float*)d_in[0];
    const int* hedefler = (const int*)d_in[1];
    const float* yuku = (const float*)d_in[2];
    const float* onbellek = (const float*)d_in[3];
    const int* secilen = (const int*)d_in[4];
    const float* strat = (const float*)d_in[5];
    const int* komsu = (const int*)d_in[6];
    const float* oyun = (const float*)d_in[7];

    const int n_tok = in_sizes[1];               // 8192
    const int V = in_sizes[0] / n_tok;           // 32000
    const int n_birim = in_sizes[2];             // 100000
    const int K = in_sizes[6] / n_birim;         // 16

    float* ws = (float*)d_ws;
    float* out = (float*)d_out;

    init_ws_kernel<<<1, 64, 0, stream>>>(ws);
    ce_kernel<<<n_tok, 256, 0, stream>>>(tahminler, hedefler, V, ws);
    stats_kernel<<<128, 256, 0, stream>>>(yuku, n_birim, ws, WS_YSUM, WS_YSQ);
    stats_kernel<<<128, 256, 0, stream>>>(oyun, n_birim, ws, WS_OSUM, WS_OSQ);
    gather_kernel<<<32, 256, 0, stream>>>(onbellek, secilen, n_tok, ws);
    suru_kernel<<<1024, 256, 0, stream>>>(strat, komsu, n_birim, K, ws);
    finalize_kernel<<<1, 64, 0, stream>>>(ws, out, n_tok, n_birim);
}

// Round 2
// 378.970 us; speedup vs baseline: 1.2081x; 1.2081x over previous
//
#include <hip/hip_runtime.h>
#include <hip/hip_bf16.h>

// ws layout (floats): 0=ce_sum 1=yuku_sum 2=yuku_sumsq 3=gather_sum 4=cos_sum 5=valid_cnt 6=oyun_sum 7=oyun_sumsq
#define WS_CE 0
#define WS_YSUM 1
#define WS_YSQ 2
#define WS_GATHER 3
#define WS_COS 4
#define WS_CNT 5
#define WS_OSUM 6
#define WS_OSQ 7

#define SURU_BLOCKS 256
#define STAT_BLOCKS 64
#define GATHER_BLOCKS 32
#define PRE_BLOCKS (SURU_BLOCKS + 2 * STAT_BLOCKS + GATHER_BLOCKS)

__device__ __forceinline__ float wave_sum(float v) {
#pragma unroll
    for (int off = 32; off > 0; off >>= 1) v += __shfl_xor(v, off, 64);
    return v;
}

__global__ void init_ws_kernel(float* ws) {
    if (threadIdx.x < 8) ws[threadIdx.x] = 0.f;
}

// rare-rescale online logsumexp update (steady state: 1 exp off-chain, 1 add on-chain)
#define LSE_UPD(m, s, v)                          \
    {                                             \
        float _v = (v);                           \
        if (_v <= m) {                            \
            s += __expf(_v - m);                  \
        } else {                                  \
            s = s * __expf(m - _v) + 1.f;         \
            m = _v;                               \
        }                                         \
    }

__global__ __launch_bounds__(256) void fused_kernel(
    const float* __restrict__ logits, const int* __restrict__ targets, int V, int n_tok,
    const float* __restrict__ yuku, const float* __restrict__ oyun, int n_birim,
    const float* __restrict__ onbellek, const int* __restrict__ secilen,
    const float* __restrict__ strat, const int* __restrict__ komsu, int K,
    float* ws) {
    __shared__ float sh_a[4], sh_b[4];
    const int b = blockIdx.x;
    const int wid = threadIdx.x >> 6;
    const int lane = threadIdx.x & 63;

    if (b >= PRE_BLOCKS) {
        // ---------------- cross-entropy: one block per row ----------------
        const int row = b - PRE_BLOCKS;
        const float* rowp = logits + (size_t)row * V;
        const float4* rp = (const float4*)rowp;
        const int nvec = V >> 2;
        float m0 = -INFINITY, m1 = -INFINITY, m2 = -INFINITY, m3 = -INFINITY;
        float s0 = 0.f, s1 = 0.f, s2 = 0.f, s3 = 0.f;
        for (int i = threadIdx.x; i < nvec; i += 256) {
            float4 v = rp[i];
            LSE_UPD(m0, s0, v.x);
            LSE_UPD(m1, s1, v.y);
            LSE_UPD(m2, s2, v.z);
            LSE_UPD(m3, s3, v.w);
        }
        // merge the 4 independent chains
        float m = fmaxf(fmaxf(m0, m1), fmaxf(m2, m3));
        float s = s0 * __expf(m0 - m) + s1 * __expf(m1 - m) +
                  s2 * __expf(m2 - m) + s3 * __expf(m3 - m);
        // wave-level (m, s) combine
#pragma unroll
        for (int off = 32; off > 0; off >>= 1) {
            float om = __shfl_xor(m, off, 64);
            float os = __shfl_xor(s, off, 64);
            float nm = fmaxf(m, om);
            s = s * __expf(m - nm) + os * __expf(om - nm);
            m = nm;
        }
        if (lane == 0) { sh_a[wid] = m; sh_b[wid] = s; }
        __syncthreads();
        if (threadIdx.x == 0) {
            float M = sh_a[0], S = sh_b[0];
#pragma unroll
            for (int w = 1; w < 4; ++w) {
                float nm = fmaxf(M, sh_a[w]);
                S = S * __expf(M - nm) + sh_b[w] * __expf(sh_a[w] - nm);
                M = nm;
            }
            float xt = rowp[targets[row]];
            atomicAdd(ws + WS_CE, M + logf(S) - xt);
        }
        return;
    }

    if (b < SURU_BLOCKS) {
        // ---------------- swarm cohesion: one wave per unit ----------------
        const int nwave = SURU_BLOCKS * 4;
        float cos_sum = 0.f, cnt = 0.f;
        for (int u = b * 4 + wid; u < n_birim; u += nwave) {
            float own = strat[(size_t)u * 64 + lane];
            const int* kp = komsu + (size_t)u * K;
            float acc = 0.f;
#pragma unroll 4
            for (int k = 0; k < K; ++k)
                acc += strat[(size_t)kp[k] * 64 + lane];
            float ort = acc / (float)K;
            float dot = wave_sum(own * ort);
            float b2 = wave_sum(own * own);
            float k2 = wave_sum(ort * ort);
            float bn = sqrtf(b2), knrm = sqrtf(k2);
            if (bn > 1e-8f && knrm > 1e-8f) {
                cos_sum += dot / (bn * knrm);
                cnt += 1.f;
            }
        }
        if (lane == 0) { sh_a[wid] = cos_sum; sh_b[wid] = cnt; }
        __syncthreads();
        if (threadIdx.x == 0) {
            atomicAdd(ws + WS_COS, sh_a[0] + sh_a[1] + sh_a[2] + sh_a[3]);
            atomicAdd(ws + WS_CNT, sh_b[0] + sh_b[1] + sh_b[2] + sh_b[3]);
        }
        return;
    }

    if (b < SURU_BLOCKS + 2 * STAT_BLOCKS) {
        // ---------------- var/mean stats on yuku or oyun ----------------
        const int sb = b - SURU_BLOCKS;
        const bool is_oyun = sb >= STAT_BLOCKS;
        const int sbb = is_oyun ? sb - STAT_BLOCKS : sb;
        const float* x = is_oyun ? oyun : yuku;
        const int sum_idx = is_oyun ? WS_OSUM : WS_YSUM;
        const int sq_idx = is_oyun ? WS_OSQ : WS_YSQ;
        float s = 0.f, sq = 0.f;
        for (int i = sbb * 256 + threadIdx.x; i < n_birim; i += STAT_BLOCKS * 256) {
            float v = x[i];
            s += v;
            sq += v * v;
        }
        s = wave_sum(s);
        sq = wave_sum(sq);
        if (lane == 0) { sh_a[wid] = s; sh_b[wid] = sq; }
        __syncthreads();
        if (threadIdx.x == 0) {
            atomicAdd(ws + sum_idx, sh_a[0] + sh_a[1] + sh_a[2] + sh_a[3]);
            atomicAdd(ws + sq_idx, sh_b[0] + sh_b[1] + sh_b[2] + sh_b[3]);
        }
        return;
    }

    // ---------------- cache hit-rate gather ----------------
    {
        const int gb = b - SURU_BLOCKS - 2 * STAT_BLOCKS;
        float s = 0.f;
        for (int i = gb * 256 + threadIdx.x; i < n_tok; i += GATHER_BLOCKS * 256)
            s += onbellek[secilen[i]];
        s = wave_sum(s);
        if (lane == 0) sh_a[wid] = s;
        __syncthreads();
        if (threadIdx.x == 0)
            atomicAdd(ws + WS_GATHER, sh_a[0] + sh_a[1] + sh_a[2] + sh_a[3]);
    }
}

__global__ void finalize_kernel(const float* __restrict__ ws, float* __restrict__ out,
                                int n_tok, int n_birim) {
    if (threadIdx.x != 0 || blockIdx.x != 0) return;
    const float n = (float)n_birim;
    float temel = ws[WS_CE] / (float)n_tok;

    float ysum = ws[WS_YSUM];
    float ymean = ysum / n;
    float yvar = (ws[WS_YSQ] - ysum * ysum / n) / (n - 1.f);
    float denge = yvar / (ymean + 1e-8f);

    float cpu = ws[WS_GATHER] / (float)n_tok;

    float cnt = ws[WS_CNT];
    float uyum = cnt > 0.f ? ws[WS_COS] / fmaxf(cnt, 1.f) : 0.f;
    float suru = (uyum + 1.f) * 0.5f;

    float osum = ws[WS_OSUM];
    float omean = osum / n;
    float ovar = (ws[WS_OSQ] - osum * osum / n) / (n - 1.f);
    float nash = ovar / (omean + 1e-8f);

    float toplam = 1.0f * temel + 0.1f * denge - 0.05f * cpu - 0.03f * suru + 0.02f * nash;
    out[0] = toplam;
    out[1] = temel;
    out[2] = denge;
    out[3] = cpu;
    out[4] = suru;
    out[5] = nash;
}

extern "C" void kernel_launch(void* const* d_in, const int* in_sizes, int n_in,
                              void* d_out, int out_size, void* d_ws, size_t ws_size,
                              hipStream_t stream) {
    const float* tahminler = (const float*)d_in[0];
    const int* hedefler = (const int*)d_in[1];
    const float* yuku = (const float*)d_in[2];
    const float* onbellek = (const float*)d_in[3];
    const int* secilen = (const int*)d_in[4];
    const float* strat = (const float*)d_in[5];
    const int* komsu = (const int*)d_in[6];
    const float* oyun = (const float*)d_in[7];

    const int n_tok = in_sizes[1];               // 8192
    const int V = in_sizes[0] / n_tok;           // 32000
    const int n_birim = in_sizes[2];             // 100000
    const int K = in_sizes[6] / n_birim;         // 16

    float* ws = (float*)d_ws;
    float* out = (float*)d_out;

    init_ws_kernel<<<1, 64, 0, stream>>>(ws);
    fused_kernel<<<PRE_BLOCKS + n_tok, 256, 0, stream>>>(
        tahminler, hedefler, V, n_tok,
        yuku, oyun, n_birim,
        onbellek, secilen,
        strat, komsu, K, ws);
    finalize_kernel<<<1, 64, 0, stream>>>(ws, out, n_tok, n_birim);
}